// Round 18
// baseline (115.920 us; speedup 1.0000x reference)
//
#include <hip/hip_runtime.h>
#include <hip/hip_bf16.h>
#include <math.h>

#define DDIM 768
#define NCLS 256
#define NFEAT 768
#define NTOK 1024
#define NBATCH 4
#define KSEL 128

typedef float f32x4 __attribute__((ext_vector_type(4)));
typedef float f32x2 __attribute__((ext_vector_type(2)));
typedef short s16x8 __attribute__((ext_vector_type(8)));

// ---------------- helpers ----------------
__device__ __forceinline__ float wsum(float v) {
#pragma unroll
  for (int o = 32; o; o >>= 1) v += __shfl_down(v, o, 64);
  return v;
}
__device__ __forceinline__ float wmaxr(float v) {
#pragma unroll
  for (int o = 32; o; o >>= 1) v = fmaxf(v, __shfl_down(v, o, 64));
  return v;
}
__device__ __forceinline__ short f2bf(float f) {
  union { __hip_bfloat16 h; short s; } u;
  u.h = __float2bfloat16(f);
  return u.s;
}
__device__ __forceinline__ float bf2f(short s) {
  union { unsigned u; float f; } c;
  c.u = ((unsigned)(unsigned short)s) << 16;
  return c.f;
}
__device__ __forceinline__ f32x2 bfpair(unsigned w) {
  f32x2 r;
  r.x = __uint_as_float(w << 16);
  r.y = __uint_as_float(w & 0xffff0000u);
  return r;
}
__device__ __forceinline__ void cvt8(float4 x, float4 y, s16x8& h, s16x8& l) {
  float v[8] = {x.x, x.y, x.z, x.w, y.x, y.y, y.z, y.w};
#pragma unroll
  for (int i = 0; i < 8; ++i) {
    short hh = f2bf(v[i]);
    h[i] = hh;
    l[i] = f2bf(v[i] - bf2f(hh));
  }
}
// LDS address swizzle: 32-short (64B) rows, 8-short (16B) chunks.
__device__ __forceinline__ int swz(int row, int chunk) {
  return (row << 5) + (((chunk ^ (row >> 1)) & 3) << 3);
}

// -------- merged prep: blocks 0..2303 = weight transpose+cvt,
//          blocks 2304..3839 = X pack (concat(cls,feats) -> hi/lo) -------
__global__ __launch_bounds__(256) void prep_all(
    const float* __restrict__ cls, const float* __restrict__ feats,
    const float* __restrict__ w0, const float* __restrict__ w1,
    const float* __restrict__ w2, const float* __restrict__ w3,
    short* __restrict__ h0, short* __restrict__ h1, short* __restrict__ h2,
    short* __restrict__ h3, short* __restrict__ l0, short* __restrict__ l1,
    short* __restrict__ Xh, short* __restrict__ Xl) {
  __shared__ float tile[32][33];
  const int bid = blockIdx.x;
  const int t = threadIdx.x;
  if (bid < 2304) {
    const int z = bid / 576, rem = bid % 576;
    const int by = rem / 24, bx = rem % 24;
    const float* s = z == 0 ? w0 : z == 1 ? w1 : z == 2 ? w2 : w3;
    short* dh = z == 0 ? h0 : z == 1 ? h1 : z == 2 ? h2 : h3;
    short* dl = z == 0 ? l0 : z == 1 ? l1 : nullptr;
    const int tx = t & 31, ty0 = t >> 5;
    const int r0 = by * 32, c0 = bx * 32;
#pragma unroll
    for (int i = 0; i < 4; ++i) {
      int ty = ty0 + i * 8;
      tile[ty][tx] = s[(size_t)(r0 + ty) * DDIM + c0 + tx];
    }
    __syncthreads();
#pragma unroll
    for (int i = 0; i < 4; ++i) {
      int ty = ty0 + i * 8;
      float v = tile[tx][ty];
      short hh = f2bf(v);
      dh[(size_t)(c0 + ty) * DDIM + r0 + tx] = hh;
      if (dl) dl[(size_t)(c0 + ty) * DDIM + r0 + tx] = f2bf(v - bf2f(hh));
    }
  } else {
    const size_t base = ((size_t)(bid - 2304) * 256 + t) * 8;
    const int row = (int)(base / DDIM);
    const int col = (int)(base % DDIM);
    const int b = row >> 10, rr = row & 1023;
    const float* src =
        (rr < NCLS) ? cls + ((size_t)b * NCLS + rr) * DDIM + col
                    : feats + ((size_t)b * NFEAT + (rr - NCLS)) * DDIM + col;
    float4 a0 = *(const float4*)(src);
    float4 a1 = *(const float4*)(src + 4);
    s16x8 h, l;
    cvt8(a0, a1, h, l);
    *(s16x8*)(Xh + base) = h;
    *(s16x8*)(Xl + base) = l;
  }
}

// -------- front GEMM (fused e_h | e_t), 128x64 tiles, split-bf16 --------
__global__ __launch_bounds__(256) void gemm_front(
    const short* __restrict__ Xh, const short* __restrict__ Xl,
    const short* __restrict__ WhT_h, const short* __restrict__ WhT_l,
    const float* __restrict__ Whb, const short* __restrict__ WtT_h,
    const short* __restrict__ WtT_l, const float* __restrict__ Wtb,
    short* __restrict__ eh_hi, short* __restrict__ eh_lo,
    short* __restrict__ et_hi, short* __restrict__ et_lo) {
  __shared__ short Ah[128 * 32], Al[128 * 32];
  __shared__ short Bh[64 * 32], Bl[64 * 32];
  const int bid = blockIdx.x;
  const int xcd = bid & 7, idx = bid >> 3;
  const int ytile = xcd * 5 + idx / 12;
  const int xtile = idx % 12;
  const int t = threadIdx.x;
  const int row0 = ytile * 128, col0 = xtile * 64;
  const bool head = row0 < 1024;

  const int ar = t >> 1, ac = (t & 1) * 2;
  const int aw0 = swz(ar, ac), aw1 = swz(ar, ac + 1);
  size_t xrow;
  {
    int gr = row0 + ar;
    xrow = head ? (size_t)(((gr >> 8) << 10) + (gr & 255)) : (size_t)(gr - 1024);
  }
  const short* aph = Xh + xrow * DDIM + ac * 8;
  const short* apl = Xl + xrow * DDIM + ac * 8;
  const int br = t >> 2, bc = t & 3;
  const int bw0 = swz(br, bc);
  const short* bph = (head ? WhT_h : WtT_h) + (size_t)(col0 + br) * DDIM + bc * 8;
  const short* bpl = (head ? WhT_l : WtT_l) + (size_t)(col0 + br) * DDIM + bc * 8;
  const float* biasu = head ? Whb : Wtb;

  const int lane = t & 63, wave = t >> 6;
  const int wr = wave >> 1, wc = wave & 1;
  const int fr = lane & 15, fq = lane >> 4;

  f32x4 acc[4][2] = {};
  s16x8 rah0 = *(const s16x8*)(aph);
  s16x8 rah1 = *(const s16x8*)(aph + 8);
  s16x8 ral0 = *(const s16x8*)(apl);
  s16x8 ral1 = *(const s16x8*)(apl + 8);
  s16x8 rbh = *(const s16x8*)(bph);
  s16x8 rbl = *(const s16x8*)(bpl);

  for (int kt = 0; kt < 24; ++kt) {
    __syncthreads();
    *(s16x8*)&Ah[aw0] = rah0;
    *(s16x8*)&Ah[aw1] = rah1;
    *(s16x8*)&Al[aw0] = ral0;
    *(s16x8*)&Al[aw1] = ral1;
    *(s16x8*)&Bh[bw0] = rbh;
    *(s16x8*)&Bl[bw0] = rbl;
    __syncthreads();
    const int kn = (kt < 23 ? kt + 1 : 23) * 32;
    rah0 = *(const s16x8*)(aph + kn);
    rah1 = *(const s16x8*)(aph + kn + 8);
    ral0 = *(const s16x8*)(apl + kn);
    ral1 = *(const s16x8*)(apl + kn + 8);
    rbh = *(const s16x8*)(bph + kn);
    rbl = *(const s16x8*)(bpl + kn);

    s16x8 afh[4], afl[4];
#pragma unroll
    for (int m = 0; m < 4; ++m) {
      int ao = swz(wr * 64 + m * 16 + fr, fq);
      afh[m] = *(const s16x8*)&Ah[ao];
      afl[m] = *(const s16x8*)&Al[ao];
    }
#pragma unroll
    for (int n = 0; n < 2; ++n) {
      int bo = swz(wc * 32 + n * 16 + fr, fq);
      s16x8 bfh = *(const s16x8*)&Bh[bo];
      s16x8 bfl = *(const s16x8*)&Bl[bo];
#pragma unroll
      for (int m = 0; m < 4; ++m) {
        acc[m][n] =
            __builtin_amdgcn_mfma_f32_16x16x32_bf16(afh[m], bfh, acc[m][n], 0, 0, 0);
        acc[m][n] =
            __builtin_amdgcn_mfma_f32_16x16x32_bf16(afh[m], bfl, acc[m][n], 0, 0, 0);
        acc[m][n] =
            __builtin_amdgcn_mfma_f32_16x16x32_bf16(afl[m], bfh, acc[m][n], 0, 0, 0);
      }
    }
  }

  short* Ch = head ? eh_hi : et_hi;
  short* Cl = head ? eh_lo : et_lo;
  const int rbase = head ? row0 : row0 - 1024;
#pragma unroll
  for (int m = 0; m < 4; ++m) {
#pragma unroll
    for (int n = 0; n < 2; ++n) {
#pragma unroll
      for (int r = 0; r < 4; ++r) {
        int rg = rbase + wr * 64 + m * 16 + fq * 4 + r;
        int cg = col0 + wc * 32 + n * 16 + fr;
        float v = acc[m][n][r] + biasu[cg];
        size_t o = (size_t)rg * DDIM + cg;
        short hh = f2bf(v);
        Ch[o] = hh;
        Cl[o] = f2bf(v - bf2f(hh));
      }
    }
  }
}

// -------- logits GEMM: 32x64 tiles, swizzled LDS, 512 blocks ------------
__global__ __launch_bounds__(256) void gemm_logits(
    const short* __restrict__ eh_hi, const short* __restrict__ eh_lo,
    const short* __restrict__ et_hi, const short* __restrict__ et_lo,
    float* __restrict__ logits, float scale) {
  __shared__ short Ah[32 * 32], Al[32 * 32];
  __shared__ short Bh[64 * 32], Bl[64 * 32];
  const int bid = blockIdx.x;
  const int xcd = bid & 7, idx = bid >> 3;
  const int batch = xcd >> 1;
  const int sub = ((xcd & 1) << 6) | idx;
  const int xtile = sub & 15, ytile = sub >> 4;
  const int row0 = ytile * 32, col0 = xtile * 64;
  const int t = threadIdx.x;

  const int ahalf = t >> 7, ac2 = t & 127;
  const int asr = ac2 >> 2, acc_ = ac2 & 3;
  const short* aptr = (ahalf ? eh_lo : eh_hi) +
                      ((size_t)batch * NCLS + row0 + asr) * DDIM + acc_ * 8;
  const int aso = swz(asr, acc_);
  const int bsr = t >> 2, bcc = t & 3;
  const short* bph = et_hi + ((size_t)batch * NTOK + col0 + bsr) * DDIM + bcc * 8;
  const short* bpl = et_lo + ((size_t)batch * NTOK + col0 + bsr) * DDIM + bcc * 8;
  const int bso = swz(bsr, bcc);

  const int lane = t & 63, wave = t >> 6;
  const int wr = wave >> 1, wc = wave & 1;
  const int fr = lane & 15, fq = lane >> 4;

  f32x4 acc[2] = {};
  s16x8 rA = *(const s16x8*)(aptr);
  s16x8 rbh = *(const s16x8*)(bph);
  s16x8 rbl = *(const s16x8*)(bpl);

  for (int kt = 0; kt < 24; ++kt) {
    __syncthreads();
    *(s16x8*)&(ahalf ? Al : Ah)[aso] = rA;
    *(s16x8*)&Bh[bso] = rbh;
    *(s16x8*)&Bl[bso] = rbl;
    __syncthreads();
    const int kn = (kt < 23 ? kt + 1 : 23) * 32;
    rA = *(const s16x8*)(aptr + kn);
    rbh = *(const s16x8*)(bph + kn);
    rbl = *(const s16x8*)(bpl + kn);
    int ao = swz(wr * 16 + fr, fq);
    s16x8 afh = *(const s16x8*)&Ah[ao];
    s16x8 afl = *(const s16x8*)&Al[ao];
#pragma unroll
    for (int n = 0; n < 2; ++n) {
      int bo = swz(wc * 32 + n * 16 + fr, fq);
      s16x8 bfh = *(const s16x8*)&Bh[bo];
      s16x8 bfl = *(const s16x8*)&Bl[bo];
      acc[n] = __builtin_amdgcn_mfma_f32_16x16x32_bf16(afh, bfh, acc[n], 0, 0, 0);
      acc[n] = __builtin_amdgcn_mfma_f32_16x16x32_bf16(afh, bfl, acc[n], 0, 0, 0);
      acc[n] = __builtin_amdgcn_mfma_f32_16x16x32_bf16(afl, bfh, acc[n], 0, 0, 0);
    }
  }

  float* Cb = logits + (size_t)batch * NCLS * NTOK;
#pragma unroll
  for (int n = 0; n < 2; ++n)
#pragma unroll
    for (int r = 0; r < 4; ++r) {
      int rg = row0 + wr * 16 + fq * 4 + r;
      int cg = col0 + wc * 32 + n * 16 + fr;
      Cb[(size_t)rg * NTOK + cg] = scale * acc[n][r];
    }
}

// -------- fused select+agg, 512 threads/row: 8-way-replicated-hist radix,
//          p-softmax, Pade-tanh gated dots (idx-upfront, 2-deep prefetch),
//          ka-softmax, weighted sum ------------------------------------
__global__ __launch_bounds__(512) void select_agg(
    const float* __restrict__ logits, const short* __restrict__ eh_hi,
    const short* __restrict__ et_hi, const float* __restrict__ cls,
    short* __restrict__ inbf) {
  const int bid = blockIdx.x;
  const int xcd = bid & 7, slot = bid >> 3;
  const int batch = xcd >> 1;
  const int row = batch * 256 + (xcd & 1) * 128 + slot;
  const int t = threadIdx.x, lane = t & 63, wave = t >> 6;  // wave 0..7

  __shared__ int hist[8][256];
  __shared__ int sh_bin, sh_rem;
  __shared__ int cnt;
  __shared__ int wsumT[8];
  __shared__ float p_sh[KSEL];
  __shared__ int idx_sh[KSEL];
  __shared__ float kaw_sh[KSEL];
  __shared__ float red[2];

  // ---- phase A: radix select top-128 (2 keys/thread, replicated hist) ----
  float2 v2 = *(const float2*)(logits + (size_t)row * NTOK + 2 * t);
  float val[2] = {v2.x, v2.y};
  unsigned key[2];
#pragma unroll
  for (int i = 0; i < 2; ++i) {
    unsigned u = __float_as_uint(val[i]);
    key[i] = (u & 0x80000000u) ? ~u : (u | 0x80000000u);
  }
  unsigned pref = 0, mask = 0;
  int rem = KSEL;
#pragma unroll
  for (int shift = 24; shift >= 0; shift -= 8) {
    int* hflat = &hist[0][0];
    hflat[t] = 0;
    hflat[t + 512] = 0;
    hflat[t + 1024] = 0;
    hflat[t + 1536] = 0;
    __syncthreads();
#pragma unroll
    for (int i = 0; i < 2; ++i)
      if ((key[i] & mask) == pref)
        atomicAdd(&hist[wave][(key[i] >> shift) & 255], 1);
    __syncthreads();
    if (wave == 0) {
      int h0 = 0, h1 = 0, h2 = 0, h3 = 0;
#pragma unroll
      for (int w = 0; w < 8; ++w) {
        h0 += hist[w][4 * lane];
        h1 += hist[w][4 * lane + 1];
        h2 += hist[w][4 * lane + 2];
        h3 += hist[w][4 * lane + 3];
      }
      int s = h0 + h1 + h2 + h3;
#pragma unroll
      for (int o = 1; o < 64; o <<= 1) {
        int v = __shfl_down(s, o, 64);
        if (lane + o < 64) s += v;
      }
      int abv = __shfl_down(s, 1, 64);
      if (lane == 63) abv = 0;
      int c3 = abv + h3, c2 = c3 + h2, c1 = c2 + h1, c0 = c1 + h0;
      int bin = -1, nab = 0;
      if (c3 >= rem && abv < rem) { bin = 4 * lane + 3; nab = abv; }
      else if (c2 >= rem && c3 < rem) { bin = 4 * lane + 2; nab = c3; }
      else if (c1 >= rem && c2 < rem) { bin = 4 * lane + 1; nab = c2; }
      else if (c0 >= rem && c1 < rem) { bin = 4 * lane + 0; nab = c1; }
      if (bin >= 0) { sh_bin = bin; sh_rem = rem - nab; }
    }
    __syncthreads();
    pref |= ((unsigned)sh_bin) << shift;
    mask |= 0xFFu << shift;
    rem = sh_rem;
  }
  const unsigned T = pref;
  const int above = KSEL - rem;

  if (t == 0) cnt = 0;
  int tc = (key[0] == T) + (key[1] == T);
  int inc = tc;
#pragma unroll
  for (int o = 1; o < 64; o <<= 1) {
    int v = __shfl_up(inc, o, 64);
    if (lane >= o) inc += v;
  }
  if (lane == 63) wsumT[wave] = inc;
  __syncthreads();
  int wbase = 0;
#pragma unroll
  for (int w = 0; w < 8; ++w)
    if (w < wave) wbase += wsumT[w];
  int excl = wbase + inc - tc;
#pragma unroll
  for (int i = 0; i < 2; ++i) {
    if (key[i] > T) {
      int s2 = atomicAdd(&cnt, 1);
      p_sh[s2] = val[i];
      idx_sh[s2] = 2 * t + i;
    } else if (key[i] == T) {
      int r = excl++;
      if (r < rem) {
        p_sh[above + r] = val[i];
        idx_sh[above + r] = 2 * t + i;
      }
    }
  }
  __syncthreads();

  // ---- phase B: softmax over p_sh ----
  if (wave == 0) {
    float m = wmaxr(fmaxf(p_sh[lane], p_sh[lane + 64]));
    if (!lane) red[0] = m;
  }
  __syncthreads();
  if (t < KSEL) p_sh[t] = __expf(p_sh[t] - red[0]);
  __syncthreads();
  if (wave == 0) {
    float s = wsum(p_sh[lane] + p_sh[lane + 64]);
    if (!lane) red[1] = s;
  }
  __syncthreads();
  if (t < KSEL) p_sh[t] *= (1.f / red[1]);
  __syncthreads();

  // ---- phase C: Pade-tanh gated dots, 16 j/wave, idx upfront,
  //      2-deep prefetch ----
  f32x2 eh2[6];
  {
    const short* ehrow = eh_hi + (size_t)row * DDIM;
    s16x8 e8 = *(const s16x8*)(ehrow + 8 * lane);
    short4 e4 = *(const short4*)(ehrow + 512 + 4 * lane);
    const unsigned* w8 = (const unsigned*)&e8;
    const unsigned* w4 = (const unsigned*)&e4;
#pragma unroll
    for (int i = 0; i < 4; ++i) eh2[i] = bfpair(w8[i]);
    eh2[4] = bfpair(w4[0]);
    eh2[5] = bfpair(w4[1]);
  }
  const short* etb = et_hi + (size_t)batch * NTOK * DDIM;

  {
    const int jb = wave * 16;
    int jidx[16];
#pragma unroll
    for (int i = 0; i < 16; ++i) jidx[i] = idx_sh[jb + i];
    s16x8 pf8[2];
    short4 pf4[2];
    {
      const short* n0 = etb + (size_t)jidx[0] * DDIM;
      pf8[0] = *(const s16x8*)(n0 + 8 * lane);
      pf4[0] = *(const short4*)(n0 + 512 + 4 * lane);
      const short* n1 = etb + (size_t)jidx[1] * DDIM;
      pf8[1] = *(const s16x8*)(n1 + 8 * lane);
      pf4[1] = *(const short4*)(n1 + 512 + 4 * lane);
    }
#pragma unroll
    for (int i = 0; i < 16; ++i) {
      s16x8 n8 = pf8[i & 1];
      short4 n4 = pf4[i & 1];
      if (i + 2 < 16) {
        const short* nn = etb + (size_t)jidx[i + 2] * DDIM;
        pf8[i & 1] = *(const s16x8*)(nn + 8 * lane);
        pf4[i & 1] = *(const short4*)(nn + 512 + 4 * lane);
      }
      float pj = p_sh[jb + i];
      float a = 2.f - pj;
      f32x2 av = {a, a}, bv = {pj, pj};
      f32x2 acc2 = {0.f, 0.f};
      const unsigned* w8 = (const unsigned*)&n8;
      const unsigned* w4 = (const unsigned*)&n4;
      f32x2 nq2[6];
#pragma unroll
      for (int q = 0; q < 4; ++q) nq2[q] = bfpair(w8[q]);
      nq2[4] = bfpair(w4[0]);
      nq2[5] = bfpair(w4[1]);
#pragma unroll
      for (int q = 0; q < 6; ++q) {
        // tanh(y) ~= clamp(y*(27+y^2)/(27+9y^2), -1, 1)  (Pade 3,2)
        f32x2 y = av * eh2[q] + bv * nq2[q];
        f32x2 y2 = y * y;
        f32x2 num = y * (y2 + (f32x2){27.f, 27.f});
        f32x2 den = y2 * (f32x2){9.f, 9.f} + (f32x2){27.f, 27.f};
        f32x2 r;
        r.x = __builtin_amdgcn_rcpf(den.x);
        r.y = __builtin_amdgcn_rcpf(den.y);
        f32x2 g0 = num * r;
        f32x2 g;
        g.x = fminf(fmaxf(g0.x, -1.f), 1.f);
        g.y = fminf(fmaxf(g0.y, -1.f), 1.f);
        acc2 = nq2[q] * g + acc2;
      }
      float partial = acc2.x + acc2.y;
      partial = wsum(partial);
      if (!lane) kaw_sh[jb + i] = partial;
    }
  }
  __syncthreads();

  // ---- phase D: softmax over kaw_sh ----
  if (wave == 0) {
    float m = wmaxr(fmaxf(kaw_sh[lane], kaw_sh[lane + 64]));
    if (!lane) red[0] = m;
  }
  __syncthreads();
  if (t < KSEL) kaw_sh[t] = __expf(kaw_sh[t] - red[0]);
  __syncthreads();
  if (wave == 0) {
    float s = wsum(kaw_sh[lane] + kaw_sh[lane + 64]);
    if (!lane) red[1] = s;
  }
  __syncthreads();
  if (t < KSEL) kaw_sh[t] *= (1.f / red[1]);
  __syncthreads();

  // ---- phase E: weighted sum, 384 threads x 2 elems, packed fma ----
  if (t < 384) {
    const size_t o = (size_t)row * DDIM + 2 * t;
    unsigned ehw = *(const unsigned*)(eh_hi + o);
    f32x2 eh = bfpair(ehw);
    float2 cl2 = *(const float2*)(cls + o);
    f32x2 cl = {cl2.x, cl2.y};
    f32x2 acc = {0.f, 0.f};
#pragma unroll 8
    for (int j = 0; j < KSEL; ++j) {
      float pr = kaw_sh[j];
      unsigned w = *(const unsigned*)(etb + (size_t)idx_sh[j] * DDIM + 2 * t);
      f32x2 nb = bfpair(w);
      acc = nb * (f32x2){pr, pr} + acc;
    }
    f32x2 sv = (eh + acc) * (f32x2){0.1f, 0.1f} + cl;
    f32x2 bvv = (eh * acc) * (f32x2){0.1f, 0.1f} + cl;
    short2 s2, b2;
    s2.x = f2bf(sv.x);
    s2.y = f2bf(sv.y);
    b2.x = f2bf(bvv.x);
    b2.y = f2bf(bvv.y);
    *(short2*)&inbf[o] = s2;
    *(short2*)&inbf[(size_t)(NBATCH * NCLS) * DDIM + o] = b2;
  }
}

// -------- lin GEMM fused: both lin1 & lin2 per tile -> emb directly ----
__global__ __launch_bounds__(256) void gemm_lin(
    const short* __restrict__ inbf, const short* __restrict__ L1T,
    const short* __restrict__ L2T, const float* __restrict__ b1,
    const float* __restrict__ b2, float* __restrict__ emb) {
  __shared__ short A1[32 * 32], A2[32 * 32];
  __shared__ short B1[64 * 32], B2[64 * 32];
  const int bid = blockIdx.x;
  const int xcd = bid & 7, idx = bid >> 3;
  const int ytile = xcd * 4 + idx / 12, xtile = idx % 12;
  const int t = threadIdx.x;
  const int row0 = ytile * 32, col0 = xtile * 64;

  const int ahalf = t >> 7, at = t & 127;
  const int asr = at >> 2, asc = at & 3;
  const short* aptr = inbf + (ahalf ? (size_t)1024 * DDIM : 0) +
                      (size_t)(row0 + asr) * DDIM + asc * 8;
  const int aso = swz(asr, asc);
  const int bsr = t >> 2, bsc = t & 3;
  const short* b1p = L1T + (size_t)(col0 + bsr) * DDIM + bsc * 8;
  const short* b2p = L2T + (size_t)(col0 + bsr) * DDIM + bsc * 8;
  const int bso = swz(bsr, bsc);

  const int lane = t & 63, wave = t >> 6;
  const int wr = wave >> 1, wc = wave & 1;
  const int fr = lane & 15, fq = lane >> 4;

  f32x4 acc1[2] = {}, acc2[2] = {};
  s16x8 rA = *(const s16x8*)(aptr);
  s16x8 rB1 = *(const s16x8*)(b1p);
  s16x8 rB2 = *(const s16x8*)(b2p);
  for (int kt = 0; kt < 24; ++kt) {
    __syncthreads();
    *(s16x8*)&(ahalf ? A2 : A1)[aso] = rA;
    *(s16x8*)&B1[bso] = rB1;
    *(s16x8*)&B2[bso] = rB2;
    __syncthreads();
    const int kn = (kt < 23 ? kt + 1 : 23) * 32;
    rA = *(const s16x8*)(aptr + kn);
    rB1 = *(const s16x8*)(b1p + kn);
    rB2 = *(const s16x8*)(b2p + kn);
    int ao = swz(wr * 16 + fr, fq);
    s16x8 a1f = *(const s16x8*)&A1[ao];
    s16x8 a2f = *(const s16x8*)&A2[ao];
#pragma unroll
    for (int n = 0; n < 2; ++n) {
      int bo = swz(wc * 32 + n * 16 + fr, fq);
      s16x8 b1f = *(const s16x8*)&B1[bo];
      s16x8 b2f = *(const s16x8*)&B2[bo];
      acc1[n] = __builtin_amdgcn_mfma_f32_16x16x32_bf16(a1f, b1f, acc1[n], 0, 0, 0);
      acc2[n] = __builtin_amdgcn_mfma_f32_16x16x32_bf16(a2f, b2f, acc2[n], 0, 0, 0);
    }
  }
#pragma unroll
  for (int n = 0; n < 2; ++n)
#pragma unroll
    for (int r = 0; r < 4; ++r) {
      int rg = row0 + wr * 16 + fq * 4 + r;
      int cg = col0 + wc * 32 + n * 16 + fr;
      float v1 = acc1[n][r] + b1[cg];
      v1 = v1 > 0.f ? v1 : 0.01f * v1;
      float v2 = acc2[n][r] + b2[cg];
      v2 = v2 > 0.f ? v2 : 0.01f * v2;
      emb[(size_t)rg * DDIM + cg] = v1 + v2;
    }
}

// -------- layernorm over D=768 --------
__global__ __launch_bounds__(256) void ln_kernel(const float* __restrict__ emb,
                                                 const float* __restrict__ lw,
                                                 const float* __restrict__ lb,
                                                 float* __restrict__ out) {
  const int row = blockIdx.x;
  const int t = threadIdx.x;
  const int lane = t & 63, wave = t >> 6;
  __shared__ float red[4];
  __shared__ float bs[2];
  float e[3];
#pragma unroll
  for (int c = 0; c < 3; ++c) e[c] = emb[(size_t)row * DDIM + t + 256 * c];
  float s = e[0] + e[1] + e[2];
  s = wsum(s);
  if (lane == 0) red[wave] = s;
  __syncthreads();
  if (t == 0) bs[0] = (red[0] + red[1] + red[2] + red[3]) * (1.f / DDIM);
  __syncthreads();
  float mu = bs[0];
  float q = 0.f;
#pragma unroll
  for (int c = 0; c < 3; ++c) {
    float d = e[c] - mu;
    q = fmaf(d, d, q);
  }
  q = wsum(q);
  if (lane == 0) red[wave] = q;
  __syncthreads();
  if (t == 0) bs[1] = (red[0] + red[1] + red[2] + red[3]) * (1.f / DDIM);
  __syncthreads();
  float rstd = rsqrtf(bs[1] + 1e-5f);
#pragma unroll
  for (int c = 0; c < 3; ++c) {
    int d = t + 256 * c;
    out[(size_t)row * DDIM + d] = (e[c] - mu) * rstd * lw[d] + lb[d];
  }
}

// ---------------- launch ----------------
extern "C" void kernel_launch(void* const* d_in, const int* in_sizes, int n_in,
                              void* d_out, int out_size, void* d_ws,
                              size_t ws_size, hipStream_t stream) {
  const float* cls = (const float*)d_in[0];
  const float* feats = (const float*)d_in[1];
  const float* Whw = (const float*)d_in[2];
  const float* Whb = (const float*)d_in[3];
  const float* Wtw = (const float*)d_in[4];
  const float* Wtb = (const float*)d_in[5];
  const float* l1w = (const float*)d_in[6];
  const float* l1b = (const float*)d_in[7];
  const float* l2w = (const float*)d_in[8];
  const float* l2b = (const float*)d_in[9];
  const float* lnw = (const float*)d_in[10];
  const float* lnb = (const float*)d_in[11];
  float* out = (float*)d_out;

  float* ws = (float*)d_ws;
  // layout (float units)
  float* emb = ws;                          // 786432 (lin fused output)
  short* eh_hi = (short*)(ws + 3932160);    // 786432 shorts
  short* eh_lo = eh_hi + 786432;            // (ends 4718592f)
  short* et_hi = (short*)(ws + 4718592);    // 3145728 shorts
  short* et_lo = et_hi + 3145728;           // (ends 7864320f)
  short* WhT_h = (short*)(ws + 7864320);    // 589824 shorts each
  short* WhT_l = WhT_h + 589824;
  short* WtT_h = WhT_h + 2 * 589824;
  short* WtT_l = WhT_h + 3 * 589824;        // (ends 9043968f)
  short* L1T = (short*)(ws + 9043968);      // 589824 shorts
  short* L2T = L1T + 589824;                // (ends 9633792f)
  float* logits = ws + 7864320;             // overlays WhT/WtT (dead by then)
  short* Xh = (short*)(ws + 9633792);       // X bf16 hi/lo; dead after front
  short* Xl = Xh + 3145728;                 // (ends 12779520f)
  short* inbf = (short*)(ws + 10027008);    // 2048*768 shorts (786432 f)
  (void)ws_size;
  (void)in_sizes;
  (void)n_in;
  (void)out_size;

  const float scale = 0.036084391824351615f;  // 1/sqrt(768)
  dim3 blk(256);

  // merged prep: weights (2304 blocks) + X pack (1536 blocks)
  prep_all<<<dim3(3840), blk, 0, stream>>>(cls, feats, Whw, Wtw, l1w, l2w,
                                           WhT_h, WtT_h, L1T, L2T, WhT_l,
                                           WtT_l, Xh, Xl);
  // fused e_h | e_t (480 blocks, 128x64, XCD-chunked, swizzled LDS)
  gemm_front<<<dim3(480), blk, 0, stream>>>(
      Xh, Xl, WhT_h, WhT_l, Whb, WtT_h, WtT_l, Wtb, eh_hi, eh_lo, et_hi,
      et_lo);
  // logits[b] = scale * e_h[b] @ e_t[b]^T (512 blocks, batch->XCD)
  gemm_logits<<<dim3(512), blk, 0, stream>>>(eh_hi, eh_lo, et_hi, et_lo,
                                             logits, scale);
  // fused top-128 select + both softmaxes + gated agg (1024 x 512 threads)
  select_agg<<<dim3(1024), dim3(512), 0, stream>>>(logits, eh_hi, et_hi, cls,
                                                   inbf);
  // fused lin1+lin2 -> emb (384 blocks, 32x64, XCD-chunked)
  gemm_lin<<<dim3(384), blk, 0, stream>>>(inbf, L1T, L2T, l1b, l2b, emb);
  // layernorm(emb) -> out
  ln_kernel<<<dim3(NBATCH * NCLS), blk, 0, stream>>>(emb, lnw, lnb, out);
}

// Round 19
// 110.891 us; speedup vs baseline: 1.0453x; 1.0453x over previous
//
#include <hip/hip_runtime.h>
#include <hip/hip_bf16.h>
#include <math.h>

#define DDIM 768
#define NCLS 256
#define NFEAT 768
#define NTOK 1024
#define NBATCH 4
#define KSEL 128

typedef float f32x4 __attribute__((ext_vector_type(4)));
typedef float f32x2 __attribute__((ext_vector_type(2)));
typedef short s16x8 __attribute__((ext_vector_type(8)));

#if __has_builtin(__builtin_amdgcn_exp2f)
#define EXP2F __builtin_amdgcn_exp2f
#else
#define EXP2F(x) __expf(0.6931471805599453f * (x))
#endif

// ---------------- helpers ----------------
__device__ __forceinline__ float wsum(float v) {
#pragma unroll
  for (int o = 32; o; o >>= 1) v += __shfl_down(v, o, 64);
  return v;
}
__device__ __forceinline__ float wmaxr(float v) {
#pragma unroll
  for (int o = 32; o; o >>= 1) v = fmaxf(v, __shfl_down(v, o, 64));
  return v;
}
__device__ __forceinline__ short f2bf(float f) {
  union { __hip_bfloat16 h; short s; } u;
  u.h = __float2bfloat16(f);
  return u.s;
}
__device__ __forceinline__ float bf2f(short s) {
  union { unsigned u; float f; } c;
  c.u = ((unsigned)(unsigned short)s) << 16;
  return c.f;
}
// two packed bf16 (one u32) -> two fp32
__device__ __forceinline__ f32x2 bfpair(unsigned w) {
  f32x2 r;
  r.x = __uint_as_float(w << 16);
  r.y = __uint_as_float(w & 0xffff0000u);
  return r;
}
__device__ __forceinline__ void cvt8(float4 x, float4 y, s16x8& h, s16x8& l) {
  float v[8] = {x.x, x.y, x.z, x.w, y.x, y.y, y.z, y.w};
#pragma unroll
  for (int i = 0; i < 8; ++i) {
    short hh = f2bf(v[i]);
    h[i] = hh;
    l[i] = f2bf(v[i] - bf2f(hh));
  }
}
// LDS address swizzle: 32-short (64B) rows, 8-short (16B) chunks.
__device__ __forceinline__ int swz(int row, int chunk) {
  return (row << 5) + (((chunk ^ (row >> 1)) & 3) << 3);
}

// -------- merged prep: blocks 0..2303 = weight transpose+cvt,
//          blocks 2304..3839 = X pack (concat(cls,feats) -> hi/lo) -------
__global__ __launch_bounds__(256) void prep_all(
    const float* __restrict__ cls, const float* __restrict__ feats,
    const float* __restrict__ w0, const float* __restrict__ w1,
    const float* __restrict__ w2, const float* __restrict__ w3,
    short* __restrict__ h0, short* __restrict__ h1, short* __restrict__ h2,
    short* __restrict__ h3, short* __restrict__ l0, short* __restrict__ l1,
    short* __restrict__ Xh, short* __restrict__ Xl) {
  __shared__ float tile[32][33];
  const int bid = blockIdx.x;
  const int t = threadIdx.x;
  if (bid < 2304) {
    const int z = bid / 576, rem = bid % 576;
    const int by = rem / 24, bx = rem % 24;
    const float* s = z == 0 ? w0 : z == 1 ? w1 : z == 2 ? w2 : w3;
    short* dh = z == 0 ? h0 : z == 1 ? h1 : z == 2 ? h2 : h3;
    short* dl = z == 0 ? l0 : z == 1 ? l1 : nullptr;
    const int tx = t & 31, ty0 = t >> 5;
    const int r0 = by * 32, c0 = bx * 32;
#pragma unroll
    for (int i = 0; i < 4; ++i) {
      int ty = ty0 + i * 8;
      tile[ty][tx] = s[(size_t)(r0 + ty) * DDIM + c0 + tx];
    }
    __syncthreads();
#pragma unroll
    for (int i = 0; i < 4; ++i) {
      int ty = ty0 + i * 8;
      float v = tile[tx][ty];
      short hh = f2bf(v);
      dh[(size_t)(c0 + ty) * DDIM + r0 + tx] = hh;
      if (dl) dl[(size_t)(c0 + ty) * DDIM + r0 + tx] = f2bf(v - bf2f(hh));
    }
  } else {
    const size_t base = ((size_t)(bid - 2304) * 256 + t) * 8;
    const int row = (int)(base / DDIM);
    const int col = (int)(base % DDIM);
    const int b = row >> 10, rr = row & 1023;
    const float* src =
        (rr < NCLS) ? cls + ((size_t)b * NCLS + rr) * DDIM + col
                    : feats + ((size_t)b * NFEAT + (rr - NCLS)) * DDIM + col;
    float4 a0 = *(const float4*)(src);
    float4 a1 = *(const float4*)(src + 4);
    s16x8 h, l;
    cvt8(a0, a1, h, l);
    *(s16x8*)(Xh + base) = h;
    *(s16x8*)(Xl + base) = l;
  }
}

// -------- front GEMM (fused e_h | e_t), 128x64 tiles, split-bf16,
//          bf16 hi/lo outputs only, swizzled LDS, XCD-chunked (480) -----
__global__ __launch_bounds__(256) void gemm_front(
    const short* __restrict__ Xh, const short* __restrict__ Xl,
    const short* __restrict__ WhT_h, const short* __restrict__ WhT_l,
    const float* __restrict__ Whb, const short* __restrict__ WtT_h,
    const short* __restrict__ WtT_l, const float* __restrict__ Wtb,
    short* __restrict__ eh_hi, short* __restrict__ eh_lo,
    short* __restrict__ et_hi, short* __restrict__ et_lo) {
  __shared__ short Ah[128 * 32], Al[128 * 32];
  __shared__ short Bh[64 * 32], Bl[64 * 32];
  const int bid = blockIdx.x;
  const int xcd = bid & 7, idx = bid >> 3;  // idx 0..59
  const int ytile = xcd * 5 + idx / 12;     // 0..39
  const int xtile = idx % 12;
  const int t = threadIdx.x;
  const int row0 = ytile * 128, col0 = xtile * 64;
  const bool head = row0 < 1024;

  const int ar = t >> 1, ac = (t & 1) * 2;
  const int aw0 = swz(ar, ac), aw1 = swz(ar, ac + 1);
  size_t xrow;
  {
    int gr = row0 + ar;
    xrow = head ? (size_t)(((gr >> 8) << 10) + (gr & 255)) : (size_t)(gr - 1024);
  }
  const short* aph = Xh + xrow * DDIM + ac * 8;
  const short* apl = Xl + xrow * DDIM + ac * 8;
  const int br = t >> 2, bc = t & 3;
  const int bw0 = swz(br, bc);
  const short* bph = (head ? WhT_h : WtT_h) + (size_t)(col0 + br) * DDIM + bc * 8;
  const short* bpl = (head ? WhT_l : WtT_l) + (size_t)(col0 + br) * DDIM + bc * 8;
  const float* biasu = head ? Whb : Wtb;

  const int lane = t & 63, wave = t >> 6;
  const int wr = wave >> 1, wc = wave & 1;
  const int fr = lane & 15, fq = lane >> 4;

  f32x4 acc[4][2] = {};
  s16x8 rah0 = *(const s16x8*)(aph);
  s16x8 rah1 = *(const s16x8*)(aph + 8);
  s16x8 ral0 = *(const s16x8*)(apl);
  s16x8 ral1 = *(const s16x8*)(apl + 8);
  s16x8 rbh = *(const s16x8*)(bph);
  s16x8 rbl = *(const s16x8*)(bpl);

  for (int kt = 0; kt < 24; ++kt) {
    __syncthreads();
    *(s16x8*)&Ah[aw0] = rah0;
    *(s16x8*)&Ah[aw1] = rah1;
    *(s16x8*)&Al[aw0] = ral0;
    *(s16x8*)&Al[aw1] = ral1;
    *(s16x8*)&Bh[bw0] = rbh;
    *(s16x8*)&Bl[bw0] = rbl;
    __syncthreads();
    const int kn = (kt < 23 ? kt + 1 : 23) * 32;
    rah0 = *(const s16x8*)(aph + kn);
    rah1 = *(const s16x8*)(aph + kn + 8);
    ral0 = *(const s16x8*)(apl + kn);
    ral1 = *(const s16x8*)(apl + kn + 8);
    rbh = *(const s16x8*)(bph + kn);
    rbl = *(const s16x8*)(bpl + kn);

    s16x8 afh[4], afl[4];
#pragma unroll
    for (int m = 0; m < 4; ++m) {
      int ao = swz(wr * 64 + m * 16 + fr, fq);
      afh[m] = *(const s16x8*)&Ah[ao];
      afl[m] = *(const s16x8*)&Al[ao];
    }
#pragma unroll
    for (int n = 0; n < 2; ++n) {
      int bo = swz(wc * 32 + n * 16 + fr, fq);
      s16x8 bfh = *(const s16x8*)&Bh[bo];
      s16x8 bfl = *(const s16x8*)&Bl[bo];
#pragma unroll
      for (int m = 0; m < 4; ++m) {
        acc[m][n] =
            __builtin_amdgcn_mfma_f32_16x16x32_bf16(afh[m], bfh, acc[m][n], 0, 0, 0);
        acc[m][n] =
            __builtin_amdgcn_mfma_f32_16x16x32_bf16(afh[m], bfl, acc[m][n], 0, 0, 0);
        acc[m][n] =
            __builtin_amdgcn_mfma_f32_16x16x32_bf16(afl[m], bfh, acc[m][n], 0, 0, 0);
      }
    }
  }

  short* Ch = head ? eh_hi : et_hi;
  short* Cl = head ? eh_lo : et_lo;
  const int rbase = head ? row0 : row0 - 1024;
#pragma unroll
  for (int m = 0; m < 4; ++m) {
#pragma unroll
    for (int n = 0; n < 2; ++n) {
#pragma unroll
      for (int r = 0; r < 4; ++r) {
        int rg = rbase + wr * 64 + m * 16 + fq * 4 + r;
        int cg = col0 + wc * 32 + n * 16 + fr;
        float v = acc[m][n][r] + biasu[cg];
        size_t o = (size_t)rg * DDIM + cg;
        short hh = f2bf(v);
        Ch[o] = hh;
        Cl[o] = f2bf(v - bf2f(hh));
      }
    }
  }
}

// -------- logits GEMM: 32x64 tiles, swizzled LDS, 512 blocks,
//          batch->XCD affinity, single-buffer + overlap --------
__global__ __launch_bounds__(256) void gemm_logits(
    const short* __restrict__ eh_hi, const short* __restrict__ eh_lo,
    const short* __restrict__ et_hi, const short* __restrict__ et_lo,
    float* __restrict__ logits, float scale) {
  __shared__ short Ah[32 * 32], Al[32 * 32];
  __shared__ short Bh[64 * 32], Bl[64 * 32];
  const int bid = blockIdx.x;
  const int xcd = bid & 7, idx = bid >> 3;
  const int batch = xcd >> 1;
  const int sub = ((xcd & 1) << 6) | idx;
  const int xtile = sub & 15, ytile = sub >> 4;
  const int row0 = ytile * 32, col0 = xtile * 64;
  const int t = threadIdx.x;

  const int ahalf = t >> 7, ac2 = t & 127;
  const int asr = ac2 >> 2, acc_ = ac2 & 3;
  const short* aptr = (ahalf ? eh_lo : eh_hi) +
                      ((size_t)batch * NCLS + row0 + asr) * DDIM + acc_ * 8;
  const int aso = swz(asr, acc_);
  const int bsr = t >> 2, bcc = t & 3;
  const short* bph = et_hi + ((size_t)batch * NTOK + col0 + bsr) * DDIM + bcc * 8;
  const short* bpl = et_lo + ((size_t)batch * NTOK + col0 + bsr) * DDIM + bcc * 8;
  const int bso = swz(bsr, bcc);

  const int lane = t & 63, wave = t >> 6;
  const int wr = wave >> 1, wc = wave & 1;
  const int fr = lane & 15, fq = lane >> 4;

  f32x4 acc[2] = {};
  s16x8 rA = *(const s16x8*)(aptr);
  s16x8 rbh = *(const s16x8*)(bph);
  s16x8 rbl = *(const s16x8*)(bpl);

  for (int kt = 0; kt < 24; ++kt) {
    __syncthreads();
    *(s16x8*)&(ahalf ? Al : Ah)[aso] = rA;
    *(s16x8*)&Bh[bso] = rbh;
    *(s16x8*)&Bl[bso] = rbl;
    __syncthreads();
    const int kn = (kt < 23 ? kt + 1 : 23) * 32;
    rA = *(const s16x8*)(aptr + kn);
    rbh = *(const s16x8*)(bph + kn);
    rbl = *(const s16x8*)(bpl + kn);
    int ao = swz(wr * 16 + fr, fq);
    s16x8 afh = *(const s16x8*)&Ah[ao];
    s16x8 afl = *(const s16x8*)&Al[ao];
#pragma unroll
    for (int n = 0; n < 2; ++n) {
      int bo = swz(wc * 32 + n * 16 + fr, fq);
      s16x8 bfh = *(const s16x8*)&Bh[bo];
      s16x8 bfl = *(const s16x8*)&Bl[bo];
      acc[n] = __builtin_amdgcn_mfma_f32_16x16x32_bf16(afh, bfh, acc[n], 0, 0, 0);
      acc[n] = __builtin_amdgcn_mfma_f32_16x16x32_bf16(afh, bfl, acc[n], 0, 0, 0);
      acc[n] = __builtin_amdgcn_mfma_f32_16x16x32_bf16(afl, bfh, acc[n], 0, 0, 0);
    }
  }

  float* Cb = logits + (size_t)batch * NCLS * NTOK;
#pragma unroll
  for (int n = 0; n < 2; ++n)
#pragma unroll
    for (int r = 0; r < 4; ++r) {
      int rg = row0 + wr * 16 + fq * 4 + r;
      int cg = col0 + wc * 32 + n * 16 + fr;
      Cb[(size_t)rg * NTOK + cg] = scale * acc[n][r];
    }
}

// -------- fused select+agg, 512 threads/row, packed-f32 gate math -------
__global__ __launch_bounds__(512) void select_agg(
    const float* __restrict__ logits, const short* __restrict__ eh_hi,
    const short* __restrict__ et_hi, const float* __restrict__ cls,
    short* __restrict__ inbf) {
  const int bid = blockIdx.x;
  const int xcd = bid & 7, slot = bid >> 3;
  const int batch = xcd >> 1;
  const int row = batch * 256 + (xcd & 1) * 128 + slot;
  const int t = threadIdx.x, lane = t & 63, wave = t >> 6;  // wave 0..7

  __shared__ int hist[256];
  __shared__ int sh_bin, sh_rem;
  __shared__ int cnt;
  __shared__ int wsumT[8];
  __shared__ float p_sh[KSEL];
  __shared__ int idx_sh[KSEL];
  __shared__ float kaw_sh[KSEL];
  __shared__ float red[2];

  // ---- phase A: radix select top-128 (2 keys per thread) ----
  float2 v2 = *(const float2*)(logits + (size_t)row * NTOK + 2 * t);
  float val[2] = {v2.x, v2.y};
  unsigned key[2];
#pragma unroll
  for (int i = 0; i < 2; ++i) {
    unsigned u = __float_as_uint(val[i]);
    key[i] = (u & 0x80000000u) ? ~u : (u | 0x80000000u);
  }
  unsigned pref = 0, mask = 0;
  int rem = KSEL;
#pragma unroll
  for (int shift = 24; shift >= 0; shift -= 8) {
    if (t < 256) hist[t] = 0;
    __syncthreads();
#pragma unroll
    for (int i = 0; i < 2; ++i)
      if ((key[i] & mask) == pref)
        atomicAdd(&hist[(key[i] >> shift) & 255], 1);
    __syncthreads();
    if (wave == 0) {
      int h0 = hist[4 * lane], h1 = hist[4 * lane + 1];
      int h2 = hist[4 * lane + 2], h3 = hist[4 * lane + 3];
      int s = h0 + h1 + h2 + h3;
#pragma unroll
      for (int o = 1; o < 64; o <<= 1) {
        int v = __shfl_down(s, o, 64);
        if (lane + o < 64) s += v;
      }
      int abv = __shfl_down(s, 1, 64);
      if (lane == 63) abv = 0;
      int c3 = abv + h3, c2 = c3 + h2, c1 = c2 + h1, c0 = c1 + h0;
      int bin = -1, nab = 0;
      if (c3 >= rem && abv < rem) { bin = 4 * lane + 3; nab = abv; }
      else if (c2 >= rem && c3 < rem) { bin = 4 * lane + 2; nab = c3; }
      else if (c1 >= rem && c2 < rem) { bin = 4 * lane + 1; nab = c2; }
      else if (c0 >= rem && c1 < rem) { bin = 4 * lane + 0; nab = c1; }
      if (bin >= 0) { sh_bin = bin; sh_rem = rem - nab; }
    }
    __syncthreads();
    pref |= ((unsigned)sh_bin) << shift;
    mask |= 0xFFu << shift;
    rem = sh_rem;
  }
  const unsigned T = pref;
  const int above = KSEL - rem;

  if (t == 0) cnt = 0;
  int tc = (key[0] == T) + (key[1] == T);
  int inc = tc;
#pragma unroll
  for (int o = 1; o < 64; o <<= 1) {
    int v = __shfl_up(inc, o, 64);
    if (lane >= o) inc += v;
  }
  if (lane == 63) wsumT[wave] = inc;
  __syncthreads();
  int wbase = 0;
#pragma unroll
  for (int w = 0; w < 8; ++w)
    if (w < wave) wbase += wsumT[w];
  int excl = wbase + inc - tc;
#pragma unroll
  for (int i = 0; i < 2; ++i) {
    if (key[i] > T) {
      int s2 = atomicAdd(&cnt, 1);
      p_sh[s2] = val[i];
      idx_sh[s2] = 2 * t + i;
    } else if (key[i] == T) {
      int r = excl++;
      if (r < rem) {
        p_sh[above + r] = val[i];
        idx_sh[above + r] = 2 * t + i;
      }
    }
  }
  __syncthreads();

  // ---- phase B: softmax over p_sh ----
  if (wave == 0) {
    float m = wmaxr(fmaxf(p_sh[lane], p_sh[lane + 64]));
    if (!lane) red[0] = m;
  }
  __syncthreads();
  if (t < KSEL) p_sh[t] = __expf(p_sh[t] - red[0]);
  __syncthreads();
  if (wave == 0) {
    float s = wsum(p_sh[lane] + p_sh[lane + 64]);
    if (!lane) red[1] = s;
  }
  __syncthreads();
  if (t < KSEL) p_sh[t] *= (1.f / red[1]);
  __syncthreads();

  // ---- phase C: gated ka dots, 16 j per wave, packed f32, prefetch ----
  f32x2 eh2[6];
  {
    const short* ehrow = eh_hi + (size_t)row * DDIM;
    s16x8 e8 = *(const s16x8*)(ehrow + 8 * lane);
    short4 e4 = *(const short4*)(ehrow + 512 + 4 * lane);
    const unsigned* w8 = (const unsigned*)&e8;
    const unsigned* w4 = (const unsigned*)&e4;
#pragma unroll
    for (int i = 0; i < 4; ++i) eh2[i] = bfpair(w8[i]);
    eh2[4] = bfpair(w4[0]);
    eh2[5] = bfpair(w4[1]);
  }
  const short* etb = et_hi + (size_t)batch * NTOK * DDIM;
  const float LOG2E = 1.4426950408889634f;

  {
    const int jb = wave * 16;
    const short* nb0 = etb + (size_t)idx_sh[jb] * DDIM;
    s16x8 n8 = *(const s16x8*)(nb0 + 8 * lane);
    short4 n4 = *(const short4*)(nb0 + 512 + 4 * lane);
    for (int i = 0; i < 16; ++i) {
      const int j = jb + i;
      s16x8 n8n;
      short4 n4n;
      if (i < 15) {
        const short* nbn = etb + (size_t)idx_sh[j + 1] * DDIM;
        n8n = *(const s16x8*)(nbn + 8 * lane);
        n4n = *(const short4*)(nbn + 512 + 4 * lane);
      }
      float pj = p_sh[j];
      float a2 = (4.f - 2.f * pj) * LOG2E;
      float b22 = (2.f * pj) * LOG2E;
      f32x2 av = {a2, a2}, bv = {b22, b22};
      f32x2 acc2 = {0.f, 0.f};
      const unsigned* w8 = (const unsigned*)&n8;
      const unsigned* w4 = (const unsigned*)&n4;
      f32x2 nq2[6];
#pragma unroll
      for (int q = 0; q < 4; ++q) nq2[q] = bfpair(w8[q]);
      nq2[4] = bfpair(w4[0]);
      nq2[5] = bfpair(w4[1]);
#pragma unroll
      for (int q = 0; q < 6; ++q) {
        f32x2 arg = av * eh2[q] + bv * nq2[q];      // pk_mul + pk_fma
        f32x2 ex;
        ex.x = EXP2F(arg.x);
        ex.y = EXP2F(arg.y);
        f32x2 den = ex + (f32x2){1.f, 1.f};         // pk_add
        f32x2 r;
        r.x = __builtin_amdgcn_rcpf(den.x);
        r.y = __builtin_amdgcn_rcpf(den.y);
        f32x2 g = r * (f32x2){-2.f, -2.f} + (f32x2){1.f, 1.f};  // pk_fma
        acc2 = nq2[q] * g + acc2;                    // pk_fma
      }
      float partial = acc2.x + acc2.y;
      partial = wsum(partial);
      if (!lane) kaw_sh[j] = partial;
      n8 = n8n;
      n4 = n4n;
    }
  }
  __syncthreads();

  // ---- phase D: softmax over kaw_sh ----
  if (wave == 0) {
    float m = wmaxr(fmaxf(kaw_sh[lane], kaw_sh[lane + 64]));
    if (!lane) red[0] = m;
  }
  __syncthreads();
  if (t < KSEL) kaw_sh[t] = __expf(kaw_sh[t] - red[0]);
  __syncthreads();
  if (wave == 0) {
    float s = wsum(kaw_sh[lane] + kaw_sh[lane + 64]);
    if (!lane) red[1] = s;
  }
  __syncthreads();
  if (t < KSEL) kaw_sh[t] *= (1.f / red[1]);
  __syncthreads();

  // ---- phase E: weighted sum, 384 threads x 2 elems, packed fma ----
  if (t < 384) {
    const size_t o = (size_t)row * DDIM + 2 * t;
    unsigned ehw = *(const unsigned*)(eh_hi + o);
    f32x2 eh = bfpair(ehw);
    float2 cl2 = *(const float2*)(cls + o);
    f32x2 cl = {cl2.x, cl2.y};
    f32x2 acc = {0.f, 0.f};
#pragma unroll 8
    for (int j = 0; j < KSEL; ++j) {
      float pr = kaw_sh[j];
      unsigned w = *(const unsigned*)(etb + (size_t)idx_sh[j] * DDIM + 2 * t);
      f32x2 nb = bfpair(w);
      acc = nb * (f32x2){pr, pr} + acc;  // pk_fma
    }
    f32x2 sv = (eh + acc) * (f32x2){0.1f, 0.1f} + cl;
    f32x2 bvv = (eh * acc) * (f32x2){0.1f, 0.1f} + cl;
    short2 s2, b2;
    s2.x = f2bf(sv.x);
    s2.y = f2bf(sv.y);
    b2.x = f2bf(bvv.x);
    b2.y = f2bf(bvv.y);
    *(short2*)&inbf[o] = s2;
    *(short2*)&inbf[(size_t)(NBATCH * NCLS) * DDIM + o] = b2;
  }
}

// -------- lin GEMM fused: both lin1 & lin2 per tile -> emb directly,
//          32x64 tiles, swizzled LDS, XCD-chunked (384 = 8 x 48) --------
__global__ __launch_bounds__(256) void gemm_lin(
    const short* __restrict__ inbf, const short* __restrict__ L1T,
    const short* __restrict__ L2T, const float* __restrict__ b1,
    const float* __restrict__ b2, float* __restrict__ emb) {
  __shared__ short A1[32 * 32], A2[32 * 32];
  __shared__ short B1[64 * 32], B2[64 * 32];
  const int bid = blockIdx.x;
  const int xcd = bid & 7, idx = bid >> 3;  // 0..47
  const int ytile = xcd * 4 + idx / 12, xtile = idx % 12;  // 32 x 12
  const int t = threadIdx.x;
  const int row0 = ytile * 32, col0 = xtile * 64;

  const int ahalf = t >> 7, at = t & 127;
  const int asr = at >> 2, asc = at & 3;
  const short* aptr = inbf + (ahalf ? (size_t)1024 * DDIM : 0) +
                      (size_t)(row0 + asr) * DDIM + asc * 8;
  const int aso = swz(asr, asc);
  const int bsr = t >> 2, bsc = t & 3;
  const short* b1p = L1T + (size_t)(col0 + bsr) * DDIM + bsc * 8;
  const short* b2p = L2T + (size_t)(col0 + bsr) * DDIM + bsc * 8;
  const int bso = swz(bsr, bsc);

  const int lane = t & 63, wave = t >> 6;
  const int wr = wave >> 1, wc = wave & 1;
  const int fr = lane & 15, fq = lane >> 4;

  f32x4 acc1[2] = {}, acc2[2] = {};
  s16x8 rA = *(const s16x8*)(aptr);
  s16x8 rB1 = *(const s16x8*)(b1p);
  s16x8 rB2 = *(const s16x8*)(b2p);
  for (int kt = 0; kt < 24; ++kt) {
    __syncthreads();
    *(s16x8*)&(ahalf ? A2 : A1)[aso] = rA;
    *(s16x8*)&B1[bso] = rB1;
    *(s16x8*)&B2[bso] = rB2;
    __syncthreads();
    const int kn = (kt < 23 ? kt + 1 : 23) * 32;
    rA = *(const s16x8*)(aptr + kn);
    rB1 = *(const s16x8*)(b1p + kn);
    rB2 = *(const s16x8*)(b2p + kn);
    int ao = swz(wr * 16 + fr, fq);
    s16x8 a1f = *(const s16x8*)&A1[ao];
    s16x8 a2f = *(const s16x8*)&A2[ao];
#pragma unroll
    for (int n = 0; n < 2; ++n) {
      int bo = swz(wc * 32 + n * 16 + fr, fq);
      s16x8 b1f = *(const s16x8*)&B1[bo];
      s16x8 b2f = *(const s16x8*)&B2[bo];
      acc1[n] = __builtin_amdgcn_mfma_f32_16x16x32_bf16(a1f, b1f, acc1[n], 0, 0, 0);
      acc2[n] = __builtin_amdgcn_mfma_f32_16x16x32_bf16(a2f, b2f, acc2[n], 0, 0, 0);
    }
  }
#pragma unroll
  for (int n = 0; n < 2; ++n)
#pragma unroll
    for (int r = 0; r < 4; ++r) {
      int rg = row0 + wr * 16 + fq * 4 + r;
      int cg = col0 + wc * 32 + n * 16 + fr;
      float v1 = acc1[n][r] + b1[cg];
      v1 = v1 > 0.f ? v1 : 0.01f * v1;
      float v2 = acc2[n][r] + b2[cg];
      v2 = v2 > 0.f ? v2 : 0.01f * v2;
      emb[(size_t)rg * DDIM + cg] = v1 + v2;
    }
}

// -------- layernorm over D=768 --------
__global__ __launch_bounds__(256) void ln_kernel(const float* __restrict__ emb,
                                                 const float* __restrict__ lw,
                                                 const float* __restrict__ lb,
                                                 float* __restrict__ out) {
  const int row = blockIdx.x;
  const int t = threadIdx.x;
  const int lane = t & 63, wave = t >> 6;
  __shared__ float red[4];
  __shared__ float bs[2];
  float e[3];
#pragma unroll
  for (int c = 0; c < 3; ++c) e[c] = emb[(size_t)row * DDIM + t + 256 * c];
  float s = e[0] + e[1] + e[2];
  s = wsum(s);
  if (lane == 0) red[wave] = s;
  __syncthreads();
  if (t == 0) bs[0] = (red[0] + red[1] + red[2] + red[3]) * (1.f / DDIM);
  __syncthreads();
  float mu = bs[0];
  float q = 0.f;
#pragma unroll
  for (int c = 0; c < 3; ++c) {
    float d = e[c] - mu;
    q = fmaf(d, d, q);
  }
  q = wsum(q);
  if (lane == 0) red[wave] = q;
  __syncthreads();
  if (t == 0) bs[1] = (red[0] + red[1] + red[2] + red[3]) * (1.f / DDIM);
  __syncthreads();
  float rstd = rsqrtf(bs[1] + 1e-5f);
#pragma unroll
  for (int c = 0; c < 3; ++c) {
    int d = t + 256 * c;
    out[(size_t)row * DDIM + d] = (e[c] - mu) * rstd * lw[d] + lb[d];
  }
}

// ---------------- launch ----------------
extern "C" void kernel_launch(void* const* d_in, const int* in_sizes, int n_in,
                              void* d_out, int out_size, void* d_ws,
                              size_t ws_size, hipStream_t stream) {
  const float* cls = (const float*)d_in[0];
  const float* feats = (const float*)d_in[1];
  const float* Whw = (const float*)d_in[2];
  const float* Whb = (const float*)d_in[3];
  const float* Wtw = (const float*)d_in[4];
  const float* Wtb = (const float*)d_in[5];
  const float* l1w = (const float*)d_in[6];
  const float* l1b = (const float*)d_in[7];
  const float* l2w = (const float*)d_in[8];
  const float* l2b = (const float*)d_in[9];
  const float* lnw = (const float*)d_in[10];
  const float* lnb = (const float*)d_in[11];
  float* out = (float*)d_out;

  float* ws = (float*)d_ws;
  // layout (float units)
  float* emb = ws;                          // 786432 (lin fused output)
  short* eh_hi = (short*)(ws + 3932160);    // 786432 shorts
  short* eh_lo = eh_hi + 786432;            // (ends 4718592f)
  short* et_hi = (short*)(ws + 4718592);    // 3145728 shorts
  short* et_lo = et_hi + 3145728;           // (ends 7864320f)
  short* WhT_h = (short*)(ws + 7864320);    // 589824 shorts each
  short* WhT_l = WhT_h + 589824;
  short* WtT_h = WhT_h + 2 * 589824;
  short* WtT_l = WhT_h + 3 * 589824;        // (ends 9043968f)
  short* L1T = (short*)(ws + 9043968);      // 589824 shorts
  short* L2T = L1T + 589824;                // (ends 9633792f)
  float* logits = ws + 7864320;             // overlays WhT/WtT (dead by then)
  short* Xh = (short*)(ws + 9633792);       // X bf16 hi/lo; dead after front
  short* Xl = Xh + 3145728;                 // (ends 12779520f)
  short* inbf = (short*)(ws + 10027008);    // 2048*768 shorts (786432 f)
  (void)ws_size;
  (void)in_sizes;
  (void)n_in;
  (void)out_size;

  const float scale = 0.036084391824351615f;  // 1/sqrt(768)
  dim3 blk(256);

  // merged prep: weights (2304 blocks) + X pack (1536 blocks)
  prep_all<<<dim3(3840), blk, 0, stream>>>(cls, feats, Whw, Wtw, l1w, l2w,
                                           WhT_h, WtT_h, L1T, L2T, WhT_l,
                                           WtT_l, Xh, Xl);
  // fused e_h | e_t (480 blocks, 128x64, XCD-chunked, swizzled LDS)
  gemm_front<<<dim3(480), blk, 0, stream>>>(
      Xh, Xl, WhT_h, WhT_l, Whb, WtT_h, WtT_l, Wtb, eh_hi, eh_lo, et_hi,
      et_lo);
  // logits[b] = scale * e_h[b] @ e_t[b]^T (512 blocks, batch->XCD)
  gemm_logits<<<dim3(512), blk, 0, stream>>>(eh_hi, eh_lo, et_hi, et_lo,
                                             logits, scale);
  // fused top-128 select + both softmaxes + gated agg (1024 x 512 threads)
  select_agg<<<dim3(1024), dim3(512), 0, stream>>>(logits, eh_hi, et_hi, cls,
                                                   inbf);
  // fused lin1+lin2 -> emb (384 blocks, 32x64, XCD-chunked)
  gemm_lin<<<dim3(384), blk, 0, stream>>>(inbf, L1T, L2T, l1b, l2b, emb);
  // layernorm(emb) -> out
  ln_kernel<<<dim3(NBATCH * NCLS), blk, 0, stream>>>(emb, lnw, lnb, out);
}

// Round 20
// 108.266 us; speedup vs baseline: 1.0707x; 1.0242x over previous
//
#include <hip/hip_runtime.h>
#include <hip/hip_bf16.h>
#include <math.h>

#define DDIM 768
#define NCLS 256
#define NFEAT 768
#define NTOK 1024
#define NBATCH 4
#define KSEL 128

typedef float f32x4 __attribute__((ext_vector_type(4)));
typedef float f32x2 __attribute__((ext_vector_type(2)));
typedef short s16x8 __attribute__((ext_vector_type(8)));

#if __has_builtin(__builtin_amdgcn_exp2f)
#define EXP2F __builtin_amdgcn_exp2f
#else
#define EXP2F(x) __expf(0.6931471805599453f * (x))
#endif

// ---------------- helpers ----------------
__device__ __forceinline__ float wsum(float v) {
#pragma unroll
  for (int o = 32; o; o >>= 1) v += __shfl_down(v, o, 64);
  return v;
}
__device__ __forceinline__ float wmaxr(float v) {
#pragma unroll
  for (int o = 32; o; o >>= 1) v = fmaxf(v, __shfl_down(v, o, 64));
  return v;
}
__device__ __forceinline__ short f2bf(float f) {
  union { __hip_bfloat16 h; short s; } u;
  u.h = __float2bfloat16(f);
  return u.s;
}
__device__ __forceinline__ float bf2f(short s) {
  union { unsigned u; float f; } c;
  c.u = ((unsigned)(unsigned short)s) << 16;
  return c.f;
}
// two packed bf16 (one u32) -> two fp32
__device__ __forceinline__ f32x2 bfpair(unsigned w) {
  f32x2 r;
  r.x = __uint_as_float(w << 16);
  r.y = __uint_as_float(w & 0xffff0000u);
  return r;
}
__device__ __forceinline__ void cvt8(float4 x, float4 y, s16x8& h, s16x8& l) {
  float v[8] = {x.x, x.y, x.z, x.w, y.x, y.y, y.z, y.w};
#pragma unroll
  for (int i = 0; i < 8; ++i) {
    short hh = f2bf(v[i]);
    h[i] = hh;
    l[i] = f2bf(v[i] - bf2f(hh));
  }
}
// LDS address swizzle: 32-short (64B) rows, 8-short (16B) chunks.
__device__ __forceinline__ int swz(int row, int chunk) {
  return (row << 5) + (((chunk ^ (row >> 1)) & 3) << 3);
}

// -------- merged prep: blocks 0..2303 = weight transpose+cvt,
//          blocks 2304..3839 = X pack (concat(cls,feats) -> hi/lo) -------
__global__ __launch_bounds__(256) void prep_all(
    const float* __restrict__ cls, const float* __restrict__ feats,
    const float* __restrict__ w0, const float* __restrict__ w1,
    const float* __restrict__ w2, const float* __restrict__ w3,
    short* __restrict__ h0, short* __restrict__ h1, short* __restrict__ h2,
    short* __restrict__ h3, short* __restrict__ l0, short* __restrict__ l1,
    short* __restrict__ Xh, short* __restrict__ Xl) {
  __shared__ float tile[32][33];
  const int bid = blockIdx.x;
  const int t = threadIdx.x;
  if (bid < 2304) {
    const int z = bid / 576, rem = bid % 576;
    const int by = rem / 24, bx = rem % 24;
    const float* s = z == 0 ? w0 : z == 1 ? w1 : z == 2 ? w2 : w3;
    short* dh = z == 0 ? h0 : z == 1 ? h1 : z == 2 ? h2 : h3;
    short* dl = z == 0 ? l0 : z == 1 ? l1 : nullptr;
    const int tx = t & 31, ty0 = t >> 5;
    const int r0 = by * 32, c0 = bx * 32;
#pragma unroll
    for (int i = 0; i < 4; ++i) {
      int ty = ty0 + i * 8;
      tile[ty][tx] = s[(size_t)(r0 + ty) * DDIM + c0 + tx];
    }
    __syncthreads();
#pragma unroll
    for (int i = 0; i < 4; ++i) {
      int ty = ty0 + i * 8;
      float v = tile[tx][ty];
      short hh = f2bf(v);
      dh[(size_t)(c0 + ty) * DDIM + r0 + tx] = hh;
      if (dl) dl[(size_t)(c0 + ty) * DDIM + r0 + tx] = f2bf(v - bf2f(hh));
    }
  } else {
    const size_t base = ((size_t)(bid - 2304) * 256 + t) * 8;
    const int row = (int)(base / DDIM);
    const int col = (int)(base % DDIM);
    const int b = row >> 10, rr = row & 1023;
    const float* src =
        (rr < NCLS) ? cls + ((size_t)b * NCLS + rr) * DDIM + col
                    : feats + ((size_t)b * NFEAT + (rr - NCLS)) * DDIM + col;
    float4 a0 = *(const float4*)(src);
    float4 a1 = *(const float4*)(src + 4);
    s16x8 h, l;
    cvt8(a0, a1, h, l);
    *(s16x8*)(Xh + base) = h;
    *(s16x8*)(Xl + base) = l;
  }
}

// -------- front GEMM (fused e_h | e_t), 128x64 tiles, split-bf16,
//          bf16 hi/lo outputs only, swizzled LDS, XCD-chunked (480) -----
__global__ __launch_bounds__(256) void gemm_front(
    const short* __restrict__ Xh, const short* __restrict__ Xl,
    const short* __restrict__ WhT_h, const short* __restrict__ WhT_l,
    const float* __restrict__ Whb, const short* __restrict__ WtT_h,
    const short* __restrict__ WtT_l, const float* __restrict__ Wtb,
    short* __restrict__ eh_hi, short* __restrict__ eh_lo,
    short* __restrict__ et_hi, short* __restrict__ et_lo) {
  __shared__ short Ah[128 * 32], Al[128 * 32];
  __shared__ short Bh[64 * 32], Bl[64 * 32];
  const int bid = blockIdx.x;
  const int xcd = bid & 7, idx = bid >> 3;  // idx 0..59
  const int ytile = xcd * 5 + idx / 12;     // 0..39
  const int xtile = idx % 12;
  const int t = threadIdx.x;
  const int row0 = ytile * 128, col0 = xtile * 64;
  const bool head = row0 < 1024;

  const int ar = t >> 1, ac = (t & 1) * 2;
  const int aw0 = swz(ar, ac), aw1 = swz(ar, ac + 1);
  size_t xrow;
  {
    int gr = row0 + ar;
    xrow = head ? (size_t)(((gr >> 8) << 10) + (gr & 255)) : (size_t)(gr - 1024);
  }
  const short* aph = Xh + xrow * DDIM + ac * 8;
  const short* apl = Xl + xrow * DDIM + ac * 8;
  const int br = t >> 2, bc = t & 3;
  const int bw0 = swz(br, bc);
  const short* bph = (head ? WhT_h : WtT_h) + (size_t)(col0 + br) * DDIM + bc * 8;
  const short* bpl = (head ? WhT_l : WtT_l) + (size_t)(col0 + br) * DDIM + bc * 8;
  const float* biasu = head ? Whb : Wtb;

  const int lane = t & 63, wave = t >> 6;
  const int wr = wave >> 1, wc = wave & 1;
  const int fr = lane & 15, fq = lane >> 4;

  f32x4 acc[4][2] = {};
  s16x8 rah0 = *(const s16x8*)(aph);
  s16x8 rah1 = *(const s16x8*)(aph + 8);
  s16x8 ral0 = *(const s16x8*)(apl);
  s16x8 ral1 = *(const s16x8*)(apl + 8);
  s16x8 rbh = *(const s16x8*)(bph);
  s16x8 rbl = *(const s16x8*)(bpl);

  for (int kt = 0; kt < 24; ++kt) {
    __syncthreads();
    *(s16x8*)&Ah[aw0] = rah0;
    *(s16x8*)&Ah[aw1] = rah1;
    *(s16x8*)&Al[aw0] = ral0;
    *(s16x8*)&Al[aw1] = ral1;
    *(s16x8*)&Bh[bw0] = rbh;
    *(s16x8*)&Bl[bw0] = rbl;
    __syncthreads();
    const int kn = (kt < 23 ? kt + 1 : 23) * 32;
    rah0 = *(const s16x8*)(aph + kn);
    rah1 = *(const s16x8*)(aph + kn + 8);
    ral0 = *(const s16x8*)(apl + kn);
    ral1 = *(const s16x8*)(apl + kn + 8);
    rbh = *(const s16x8*)(bph + kn);
    rbl = *(const s16x8*)(bpl + kn);

    s16x8 afh[4], afl[4];
#pragma unroll
    for (int m = 0; m < 4; ++m) {
      int ao = swz(wr * 64 + m * 16 + fr, fq);
      afh[m] = *(const s16x8*)&Ah[ao];
      afl[m] = *(const s16x8*)&Al[ao];
    }
#pragma unroll
    for (int n = 0; n < 2; ++n) {
      int bo = swz(wc * 32 + n * 16 + fr, fq);
      s16x8 bfh = *(const s16x8*)&Bh[bo];
      s16x8 bfl = *(const s16x8*)&Bl[bo];
#pragma unroll
      for (int m = 0; m < 4; ++m) {
        acc[m][n] =
            __builtin_amdgcn_mfma_f32_16x16x32_bf16(afh[m], bfh, acc[m][n], 0, 0, 0);
        acc[m][n] =
            __builtin_amdgcn_mfma_f32_16x16x32_bf16(afh[m], bfl, acc[m][n], 0, 0, 0);
        acc[m][n] =
            __builtin_amdgcn_mfma_f32_16x16x32_bf16(afl[m], bfh, acc[m][n], 0, 0, 0);
      }
    }
  }

  short* Ch = head ? eh_hi : et_hi;
  short* Cl = head ? eh_lo : et_lo;
  const int rbase = head ? row0 : row0 - 1024;
#pragma unroll
  for (int m = 0; m < 4; ++m) {
#pragma unroll
    for (int n = 0; n < 2; ++n) {
#pragma unroll
      for (int r = 0; r < 4; ++r) {
        int rg = rbase + wr * 64 + m * 16 + fq * 4 + r;
        int cg = col0 + wc * 32 + n * 16 + fr;
        float v = acc[m][n][r] + biasu[cg];
        size_t o = (size_t)rg * DDIM + cg;
        short hh = f2bf(v);
        Ch[o] = hh;
        Cl[o] = f2bf(v - bf2f(hh));
      }
    }
  }
}

// -------- logits GEMM: 32x64 tiles, swizzled LDS, 512 blocks,
//          batch->XCD affinity, single-buffer + overlap --------
__global__ __launch_bounds__(256) void gemm_logits(
    const short* __restrict__ eh_hi, const short* __restrict__ eh_lo,
    const short* __restrict__ et_hi, const short* __restrict__ et_lo,
    float* __restrict__ logits, float scale) {
  __shared__ short Ah[32 * 32], Al[32 * 32];
  __shared__ short Bh[64 * 32], Bl[64 * 32];
  const int bid = blockIdx.x;
  const int xcd = bid & 7, idx = bid >> 3;
  const int batch = xcd >> 1;
  const int sub = ((xcd & 1) << 6) | idx;
  const int xtile = sub & 15, ytile = sub >> 4;
  const int row0 = ytile * 32, col0 = xtile * 64;
  const int t = threadIdx.x;

  const int ahalf = t >> 7, ac2 = t & 127;
  const int asr = ac2 >> 2, acc_ = ac2 & 3;
  const short* aptr = (ahalf ? eh_lo : eh_hi) +
                      ((size_t)batch * NCLS + row0 + asr) * DDIM + acc_ * 8;
  const int aso = swz(asr, acc_);
  const int bsr = t >> 2, bcc = t & 3;
  const short* bph = et_hi + ((size_t)batch * NTOK + col0 + bsr) * DDIM + bcc * 8;
  const short* bpl = et_lo + ((size_t)batch * NTOK + col0 + bsr) * DDIM + bcc * 8;
  const int bso = swz(bsr, bcc);

  const int lane = t & 63, wave = t >> 6;
  const int wr = wave >> 1, wc = wave & 1;
  const int fr = lane & 15, fq = lane >> 4;

  f32x4 acc[2] = {};
  s16x8 rA = *(const s16x8*)(aptr);
  s16x8 rbh = *(const s16x8*)(bph);
  s16x8 rbl = *(const s16x8*)(bpl);

  for (int kt = 0; kt < 24; ++kt) {
    __syncthreads();
    *(s16x8*)&(ahalf ? Al : Ah)[aso] = rA;
    *(s16x8*)&Bh[bso] = rbh;
    *(s16x8*)&Bl[bso] = rbl;
    __syncthreads();
    const int kn = (kt < 23 ? kt + 1 : 23) * 32;
    rA = *(const s16x8*)(aptr + kn);
    rbh = *(const s16x8*)(bph + kn);
    rbl = *(const s16x8*)(bpl + kn);
    int ao = swz(wr * 16 + fr, fq);
    s16x8 afh = *(const s16x8*)&Ah[ao];
    s16x8 afl = *(const s16x8*)&Al[ao];
#pragma unroll
    for (int n = 0; n < 2; ++n) {
      int bo = swz(wc * 32 + n * 16 + fr, fq);
      s16x8 bfh = *(const s16x8*)&Bh[bo];
      s16x8 bfl = *(const s16x8*)&Bl[bo];
      acc[n] = __builtin_amdgcn_mfma_f32_16x16x32_bf16(afh, bfh, acc[n], 0, 0, 0);
      acc[n] = __builtin_amdgcn_mfma_f32_16x16x32_bf16(afh, bfl, acc[n], 0, 0, 0);
      acc[n] = __builtin_amdgcn_mfma_f32_16x16x32_bf16(afl, bfh, acc[n], 0, 0, 0);
    }
  }

  float* Cb = logits + (size_t)batch * NCLS * NTOK;
#pragma unroll
  for (int n = 0; n < 2; ++n)
#pragma unroll
    for (int r = 0; r < 4; ++r) {
      int rg = row0 + wr * 16 + fq * 4 + r;
      int cg = col0 + wc * 32 + n * 16 + fr;
      Cb[(size_t)rg * NTOK + cg] = scale * acc[n][r];
    }
}

// -------- fused select+agg, 512 threads/row: radix top-128, p-softmax,
//          gated dots with ONLINE ka-softmax accumulation (no phase D/E
//          regather), cross-wave combine, output ------------------------
__global__ __launch_bounds__(512) void select_agg(
    const float* __restrict__ logits, const short* __restrict__ eh_hi,
    const short* __restrict__ et_hi, const float* __restrict__ cls,
    short* __restrict__ inbf) {
  const int bid = blockIdx.x;
  const int xcd = bid & 7, slot = bid >> 3;
  const int batch = xcd >> 1;
  const int row = batch * 256 + (xcd & 1) * 128 + slot;
  const int t = threadIdx.x, lane = t & 63, wave = t >> 6;  // wave 0..7

  __shared__ int hist[256];
  __shared__ int sh_bin, sh_rem;
  __shared__ int cnt;
  __shared__ int wsumT[8];
  __shared__ float p_sh[KSEL];
  __shared__ int idx_sh[KSEL];
  __shared__ float red[2];
  __shared__ float mw_sh[8], sw_sh[8];
  __shared__ float pE_sh[8 * 64 * 13];  // [wave][lane][13] (12 used; 13 = bank spread)

  // ---- phase A: radix select top-128 (2 keys per thread) ----
  float2 v2 = *(const float2*)(logits + (size_t)row * NTOK + 2 * t);
  float val[2] = {v2.x, v2.y};
  unsigned key[2];
#pragma unroll
  for (int i = 0; i < 2; ++i) {
    unsigned u = __float_as_uint(val[i]);
    key[i] = (u & 0x80000000u) ? ~u : (u | 0x80000000u);
  }
  unsigned pref = 0, mask = 0;
  int rem = KSEL;
#pragma unroll
  for (int shift = 24; shift >= 0; shift -= 8) {
    if (t < 256) hist[t] = 0;
    __syncthreads();
#pragma unroll
    for (int i = 0; i < 2; ++i)
      if ((key[i] & mask) == pref)
        atomicAdd(&hist[(key[i] >> shift) & 255], 1);
    __syncthreads();
    if (wave == 0) {
      int h0 = hist[4 * lane], h1 = hist[4 * lane + 1];
      int h2 = hist[4 * lane + 2], h3 = hist[4 * lane + 3];
      int s = h0 + h1 + h2 + h3;
#pragma unroll
      for (int o = 1; o < 64; o <<= 1) {
        int v = __shfl_down(s, o, 64);
        if (lane + o < 64) s += v;
      }
      int abv = __shfl_down(s, 1, 64);
      if (lane == 63) abv = 0;
      int c3 = abv + h3, c2 = c3 + h2, c1 = c2 + h1, c0 = c1 + h0;
      int bin = -1, nab = 0;
      if (c3 >= rem && abv < rem) { bin = 4 * lane + 3; nab = abv; }
      else if (c2 >= rem && c3 < rem) { bin = 4 * lane + 2; nab = c3; }
      else if (c1 >= rem && c2 < rem) { bin = 4 * lane + 1; nab = c2; }
      else if (c0 >= rem && c1 < rem) { bin = 4 * lane + 0; nab = c1; }
      if (bin >= 0) { sh_bin = bin; sh_rem = rem - nab; }
    }
    __syncthreads();
    pref |= ((unsigned)sh_bin) << shift;
    mask |= 0xFFu << shift;
    rem = sh_rem;
  }
  const unsigned T = pref;
  const int above = KSEL - rem;

  if (t == 0) cnt = 0;
  int tc = (key[0] == T) + (key[1] == T);
  int inc = tc;
#pragma unroll
  for (int o = 1; o < 64; o <<= 1) {
    int v = __shfl_up(inc, o, 64);
    if (lane >= o) inc += v;
  }
  if (lane == 63) wsumT[wave] = inc;
  __syncthreads();
  int wbase = 0;
#pragma unroll
  for (int w = 0; w < 8; ++w)
    if (w < wave) wbase += wsumT[w];
  int excl = wbase + inc - tc;
#pragma unroll
  for (int i = 0; i < 2; ++i) {
    if (key[i] > T) {
      int s2 = atomicAdd(&cnt, 1);
      p_sh[s2] = val[i];
      idx_sh[s2] = 2 * t + i;
    } else if (key[i] == T) {
      int r = excl++;
      if (r < rem) {
        p_sh[above + r] = val[i];
        idx_sh[above + r] = 2 * t + i;
      }
    }
  }
  __syncthreads();

  // ---- phase B: softmax over p_sh ----
  if (wave == 0) {
    float m = wmaxr(fmaxf(p_sh[lane], p_sh[lane + 64]));
    if (!lane) red[0] = m;
  }
  __syncthreads();
  if (t < KSEL) p_sh[t] = __expf(p_sh[t] - red[0]);
  __syncthreads();
  if (wave == 0) {
    float s = wsum(p_sh[lane] + p_sh[lane + 64]);
    if (!lane) red[1] = s;
  }
  __syncthreads();
  if (t < KSEL) p_sh[t] *= (1.f / red[1]);
  __syncthreads();

  // ---- phase C: gated ka dots + online softmax accumulation ----
  f32x2 eh2[6];
  {
    const short* ehrow = eh_hi + (size_t)row * DDIM;
    s16x8 e8 = *(const s16x8*)(ehrow + 8 * lane);
    short4 e4 = *(const short4*)(ehrow + 512 + 4 * lane);
    const unsigned* w8 = (const unsigned*)&e8;
    const unsigned* w4 = (const unsigned*)&e4;
#pragma unroll
    for (int i = 0; i < 4; ++i) eh2[i] = bfpair(w8[i]);
    eh2[4] = bfpair(w4[0]);
    eh2[5] = bfpair(w4[1]);
  }
  const short* etb = et_hi + (size_t)batch * NTOK * DDIM;
  const float LOG2E = 1.4426950408889634f;

  float m_w = -3.0e38f, s_w = 0.f;
  f32x2 pE0 = {0.f, 0.f}, pE1 = {0.f, 0.f}, pE2 = {0.f, 0.f};
  f32x2 pE3 = {0.f, 0.f}, pE4 = {0.f, 0.f}, pE5 = {0.f, 0.f};
  {
    const int jb = wave * 16;
    const short* nb0 = etb + (size_t)idx_sh[jb] * DDIM;
    s16x8 n8 = *(const s16x8*)(nb0 + 8 * lane);
    short4 n4 = *(const short4*)(nb0 + 512 + 4 * lane);
    for (int i = 0; i < 16; ++i) {
      const int j = jb + i;
      s16x8 n8n;
      short4 n4n;
      if (i < 15) {
        const short* nbn = etb + (size_t)idx_sh[j + 1] * DDIM;
        n8n = *(const s16x8*)(nbn + 8 * lane);
        n4n = *(const short4*)(nbn + 512 + 4 * lane);
      }
      float pj = p_sh[j];
      float a2 = (4.f - 2.f * pj) * LOG2E;
      float b22 = (2.f * pj) * LOG2E;
      f32x2 av = {a2, a2}, bv = {b22, b22};
      f32x2 acc2 = {0.f, 0.f};
      const unsigned* w8 = (const unsigned*)&n8;
      const unsigned* w4 = (const unsigned*)&n4;
      f32x2 nq2[6];
#pragma unroll
      for (int q = 0; q < 4; ++q) nq2[q] = bfpair(w8[q]);
      nq2[4] = bfpair(w4[0]);
      nq2[5] = bfpair(w4[1]);
#pragma unroll
      for (int q = 0; q < 6; ++q) {
        f32x2 arg = av * eh2[q] + bv * nq2[q];
        f32x2 ex;
        ex.x = EXP2F(arg.x);
        ex.y = EXP2F(arg.y);
        f32x2 den = ex + (f32x2){1.f, 1.f};
        f32x2 r;
        r.x = __builtin_amdgcn_rcpf(den.x);
        r.y = __builtin_amdgcn_rcpf(den.y);
        f32x2 g = r * (f32x2){-2.f, -2.f} + (f32x2){1.f, 1.f};
        acc2 = nq2[q] * g + acc2;
      }
      float kaw = acc2.x + acc2.y;
#pragma unroll
      for (int o = 32; o; o >>= 1) kaw += __shfl_xor(kaw, o, 64);
      // online softmax update (kaw is wave-uniform)
      if (kaw > m_w) {
        float f = EXP2F((m_w - kaw) * LOG2E);
        f32x2 fv = {f, f};
        s_w *= f;
        pE0 *= fv; pE1 *= fv; pE2 *= fv;
        pE3 *= fv; pE4 *= fv; pE5 *= fv;
        m_w = kaw;
      }
      float c = EXP2F((kaw - m_w) * LOG2E);
      s_w += c;
      f32x2 cc = {c, c};
      pE0 = nq2[0] * cc + pE0;
      pE1 = nq2[1] * cc + pE1;
      pE2 = nq2[2] * cc + pE2;
      pE3 = nq2[3] * cc + pE3;
      pE4 = nq2[4] * cc + pE4;
      pE5 = nq2[5] * cc + pE5;
      n8 = n8n;
      n4 = n4n;
    }
  }
  if (!lane) {
    mw_sh[wave] = m_w;
    sw_sh[wave] = s_w;
  }
  __syncthreads();

  // ---- cross-wave combine: global max + denom, store scaled partials ----
  float gm = mw_sh[0];
#pragma unroll
  for (int w = 1; w < 8; ++w) gm = fmaxf(gm, mw_sh[w]);
  float denom = 0.f;
#pragma unroll
  for (int w = 0; w < 8; ++w) denom += sw_sh[w] * EXP2F((mw_sh[w] - gm) * LOG2E);
  {
    float fw = EXP2F((m_w - gm) * LOG2E);
    f32x2 fv = {fw, fw};
    float* base = &pE_sh[(wave * 64 + lane) * 13];
    f32x2 t0 = pE0 * fv, t1 = pE1 * fv, t2 = pE2 * fv;
    f32x2 t3 = pE3 * fv, t4 = pE4 * fv, t5 = pE5 * fv;
    base[0] = t0.x;  base[1] = t0.y;  base[2] = t1.x;  base[3] = t1.y;
    base[4] = t2.x;  base[5] = t2.y;  base[6] = t3.x;  base[7] = t3.y;
    base[8] = t4.x;  base[9] = t4.y;  base[10] = t5.x; base[11] = t5.y;
  }
  __syncthreads();

  // ---- output: reduce 8 partials per d, combine, write (t < 384) ----
  if (t < 384) {
    const int d0 = 2 * t;
    int l0, s0;
    if (d0 < 512) {
      l0 = d0 >> 3;
      s0 = d0 & 7;
    } else {
      l0 = (d0 - 512) >> 2;
      s0 = 8 + ((d0 - 512) & 3);
    }
    float sum0 = 0.f, sum1 = 0.f;
#pragma unroll
    for (int w = 0; w < 8; ++w) {
      const float* b = &pE_sh[(w * 64 + l0) * 13 + s0];
      sum0 += b[0];
      sum1 += b[1];
    }
    float inv = 1.f / denom;
    f32x2 acc = {sum0 * inv, sum1 * inv};
    const size_t o = (size_t)row * DDIM + d0;
    unsigned ehw = *(const unsigned*)(eh_hi + o);
    f32x2 eh = bfpair(ehw);
    float2 cl2 = *(const float2*)(cls + o);
    f32x2 cl = {cl2.x, cl2.y};
    f32x2 sv = (eh + acc) * (f32x2){0.1f, 0.1f} + cl;
    f32x2 bvv = (eh * acc) * (f32x2){0.1f, 0.1f} + cl;
    short2 s2, b2;
    s2.x = f2bf(sv.x);
    s2.y = f2bf(sv.y);
    b2.x = f2bf(bvv.x);
    b2.y = f2bf(bvv.y);
    *(short2*)&inbf[o] = s2;
    *(short2*)&inbf[(size_t)(NBATCH * NCLS) * DDIM + o] = b2;
  }
}

// -------- lin GEMM fused: both lin1 & lin2 per tile -> emb directly,
//          32x64 tiles, swizzled LDS, XCD-chunked (384 = 8 x 48) --------
__global__ __launch_bounds__(256) void gemm_lin(
    const short* __restrict__ inbf, const short* __restrict__ L1T,
    const short* __restrict__ L2T, const float* __restrict__ b1,
    const float* __restrict__ b2, float* __restrict__ emb) {
  __shared__ short A1[32 * 32], A2[32 * 32];
  __shared__ short B1[64 * 32], B2[64 * 32];
  const int bid = blockIdx.x;
  const int xcd = bid & 7, idx = bid >> 3;  // 0..47
  const int ytile = xcd * 4 + idx / 12, xtile = idx % 12;  // 32 x 12
  const int t = threadIdx.x;
  const int row0 = ytile * 32, col0 = xtile * 64;

  const int ahalf = t >> 7, at = t & 127;
  const int asr = at >> 2, asc = at & 3;
  const short* aptr = inbf + (ahalf ? (size_t)1024 * DDIM : 0) +
                      (size_t)(row0 + asr) * DDIM + asc * 8;
  const int aso = swz(asr, asc);
  const int bsr = t >> 2, bsc = t & 3;
  const short* b1p = L1T + (size_t)(col0 + bsr) * DDIM + bsc * 8;
  const short* b2p = L2T + (size_t)(col0 + bsr) * DDIM + bsc * 8;
  const int bso = swz(bsr, bsc);

  const int lane = t & 63, wave = t >> 6;
  const int wr = wave >> 1, wc = wave & 1;
  const int fr = lane & 15, fq = lane >> 4;

  f32x4 acc1[2] = {}, acc2[2] = {};
  s16x8 rA = *(const s16x8*)(aptr);
  s16x8 rB1 = *(const s16x8*)(b1p);
  s16x8 rB2 = *(const s16x8*)(b2p);
  for (int kt = 0; kt < 24; ++kt) {
    __syncthreads();
    *(s16x8*)&(ahalf ? A2 : A1)[aso] = rA;
    *(s16x8*)&B1[bso] = rB1;
    *(s16x8*)&B2[bso] = rB2;
    __syncthreads();
    const int kn = (kt < 23 ? kt + 1 : 23) * 32;
    rA = *(const s16x8*)(aptr + kn);
    rB1 = *(const s16x8*)(b1p + kn);
    rB2 = *(const s16x8*)(b2p + kn);
    int ao = swz(wr * 16 + fr, fq);
    s16x8 a1f = *(const s16x8*)&A1[ao];
    s16x8 a2f = *(const s16x8*)&A2[ao];
#pragma unroll
    for (int n = 0; n < 2; ++n) {
      int bo = swz(wc * 32 + n * 16 + fr, fq);
      s16x8 b1f = *(const s16x8*)&B1[bo];
      s16x8 b2f = *(const s16x8*)&B2[bo];
      acc1[n] = __builtin_amdgcn_mfma_f32_16x16x32_bf16(a1f, b1f, acc1[n], 0, 0, 0);
      acc2[n] = __builtin_amdgcn_mfma_f32_16x16x32_bf16(a2f, b2f, acc2[n], 0, 0, 0);
    }
  }
#pragma unroll
  for (int n = 0; n < 2; ++n)
#pragma unroll
    for (int r = 0; r < 4; ++r) {
      int rg = row0 + wr * 16 + fq * 4 + r;
      int cg = col0 + wc * 32 + n * 16 + fr;
      float v1 = acc1[n][r] + b1[cg];
      v1 = v1 > 0.f ? v1 : 0.01f * v1;
      float v2 = acc2[n][r] + b2[cg];
      v2 = v2 > 0.f ? v2 : 0.01f * v2;
      emb[(size_t)rg * DDIM + cg] = v1 + v2;
    }
}

// -------- layernorm over D=768 --------
__global__ __launch_bounds__(256) void ln_kernel(const float* __restrict__ emb,
                                                 const float* __restrict__ lw,
                                                 const float* __restrict__ lb,
                                                 float* __restrict__ out) {
  const int row = blockIdx.x;
  const int t = threadIdx.x;
  const int lane = t & 63, wave = t >> 6;
  __shared__ float red[4];
  __shared__ float bs[2];
  float e[3];
#pragma unroll
  for (int c = 0; c < 3; ++c) e[c] = emb[(size_t)row * DDIM + t + 256 * c];
  float s = e[0] + e[1] + e[2];
  s = wsum(s);
  if (lane == 0) red[wave] = s;
  __syncthreads();
  if (t == 0) bs[0] = (red[0] + red[1] + red[2] + red[3]) * (1.f / DDIM);
  __syncthreads();
  float mu = bs[0];
  float q = 0.f;
#pragma unroll
  for (int c = 0; c < 3; ++c) {
    float d = e[c] - mu;
    q = fmaf(d, d, q);
  }
  q = wsum(q);
  if (lane == 0) red[wave] = q;
  __syncthreads();
  if (t == 0) bs[1] = (red[0] + red[1] + red[2] + red[3]) * (1.f / DDIM);
  __syncthreads();
  float rstd = rsqrtf(bs[1] + 1e-5f);
#pragma unroll
  for (int c = 0; c < 3; ++c) {
    int d = t + 256 * c;
    out[(size_t)row * DDIM + d] = (e[c] - mu) * rstd * lw[d] + lb[d];
  }
}

// ---------------- launch ----------------
extern "C" void kernel_launch(void* const* d_in, const int* in_sizes, int n_in,
                              void* d_out, int out_size, void* d_ws,
                              size_t ws_size, hipStream_t stream) {
  const float* cls = (const float*)d_in[0];
  const float* feats = (const float*)d_in[1];
  const float* Whw = (const float*)d_in[2];
  const float* Whb = (const float*)d_in[3];
  const float* Wtw = (const float*)d_in[4];
  const float* Wtb = (const float*)d_in[5];
  const float* l1w = (const float*)d_in[6];
  const float* l1b = (const float*)d_in[7];
  const float* l2w = (const float*)d_in[8];
  const float* l2b = (const float*)d_in[9];
  const float* lnw = (const float*)d_in[10];
  const float* lnb = (const float*)d_in[11];
  float* out = (float*)d_out;

  float* ws = (float*)d_ws;
  // layout (float units)
  float* emb = ws;                          // 786432 (lin fused output)
  short* eh_hi = (short*)(ws + 3932160);    // 786432 shorts
  short* eh_lo = eh_hi + 786432;            // (ends 4718592f)
  short* et_hi = (short*)(ws + 4718592);    // 3145728 shorts
  short* et_lo = et_hi + 3145728;           // (ends 7864320f)
  short* WhT_h = (short*)(ws + 7864320);    // 589824 shorts each
  short* WhT_l = WhT_h + 589824;
  short* WtT_h = WhT_h + 2 * 589824;
  short* WtT_l = WhT_h + 3 * 589824;        // (ends 9043968f)
  short* L1T = (short*)(ws + 9043968);      // 589824 shorts
  short* L2T = L1T + 589824;                // (ends 9633792f)
  float* logits = ws + 7864320;             // overlays WhT/WtT (dead by then)
  short* Xh = (short*)(ws + 9633792);       // X bf16 hi/lo; dead after front
  short* Xl = Xh + 3145728;                 // (ends 12779520f)
  short* inbf = (short*)(ws + 10027008);    // 2048*768 shorts (786432 f)
  (void)ws_size;
  (void)in_sizes;
  (void)n_in;
  (void)out_size;

  const float scale = 0.036084391824351615f;  // 1/sqrt(768)
  dim3 blk(256);

  // merged prep: weights (2304 blocks) + X pack (1536 blocks)
  prep_all<<<dim3(3840), blk, 0, stream>>>(cls, feats, Whw, Wtw, l1w, l2w,
                                           WhT_h, WtT_h, L1T, L2T, WhT_l,
                                           WtT_l, Xh, Xl);
  // fused e_h | e_t (480 blocks, 128x64, XCD-chunked, swizzled LDS)
  gemm_front<<<dim3(480), blk, 0, stream>>>(
      Xh, Xl, WhT_h, WhT_l, Whb, WtT_h, WtT_l, Wtb, eh_hi, eh_lo, et_hi,
      et_lo);
  // logits[b] = scale * e_h[b] @ e_t[b]^T (512 blocks, batch->XCD)
  gemm_logits<<<dim3(512), blk, 0, stream>>>(eh_hi, eh_lo, et_hi, et_lo,
                                             logits, scale);
  // fused top-128 select + p-softmax + online-softmax gated agg
  select_agg<<<dim3(1024), dim3(512), 0, stream>>>(logits, eh_hi, et_hi, cls,
                                                   inbf);
  // fused lin1+lin2 -> emb (384 blocks, 32x64, XCD-chunked)
  gemm_lin<<<dim3(384), blk, 0, stream>>>(inbf, L1T, L2T, l1b, l2b, emb);
  // layernorm(emb) -> out
  ln_kernel<<<dim3(NBATCH * NCLS), blk, 0, stream>>>(emb, lnw, lnb, out);
}